// Round 1
// baseline (642.883 us; speedup 1.0000x reference)
//
#include <hip/hip_runtime.h>
#include <math.h>

#define BB 4096
#define FIN 768
#define HH 256
#define DD 128
#define NN 16384

// ---------------- transpose: out[n][k] = in[k][n], in is K x N row-major ----
__global__ void transpose_kernel(const float* __restrict__ in, float* __restrict__ out,
                                 int K, int N) {
  __shared__ float tile[32][33];
  int k0 = blockIdx.y * 32, n0 = blockIdx.x * 32;
  int tx = threadIdx.x, ty = threadIdx.y; // 32 x 8
  for (int r = ty; r < 32; r += 8) {
    tile[r][tx] = in[(size_t)(k0 + r) * N + (n0 + tx)];
  }
  __syncthreads();
  for (int r = ty; r < 32; r += 8) {
    out[(size_t)(n0 + r) * K + (k0 + tx)] = tile[tx][r];
  }
}

// ---------------- prototype squared norms ----------------
__global__ void proto_norms(const float* __restrict__ p, float* __restrict__ An) {
  int row = blockIdx.x * 4 + (threadIdx.x >> 6);
  int lane = threadIdx.x & 63;
  float v0 = p[(size_t)row * DD + lane], v1 = p[(size_t)row * DD + 64 + lane];
  float s = v0 * v0 + v1 * v1;
  for (int off = 32; off; off >>= 1) s += __shfl_xor(s, off);
  if (lane == 0) An[row] = s;
}

// ---------------- expmap0 + stable (1 - 3*Bn) in fp64 ----------------
__global__ void expmap_kernel(const float* __restrict__ u, float* __restrict__ hyp,
                              float* __restrict__ sB) {
  int row = blockIdx.x * 4 + (threadIdx.x >> 6);
  int lane = threadIdx.x & 63;
  float u0 = u[(size_t)row * DD + lane], u1 = u[(size_t)row * DD + 64 + lane];
  double s = (double)u0 * u0 + (double)u1 * u1;
  for (int off = 32; off; off >>= 1) s += __shfl_xor(s, off);
  double un = sqrt(s);
  if (un < 1e-15) un = 1e-15;
  double t = 1.7320508075688772 * un;
  double factor = tanh(t) / t;
  float h0 = (float)(factor * u0), h1 = (float)(factor * u1);
  hyp[(size_t)row * DD + lane] = h0;
  hyp[(size_t)row * DD + 64 + lane] = h1;
  double bs = (double)h0 * h0 + (double)h1 * h1;
  for (int off = 32; off; off >>= 1) bs += __shfl_xor(bs, off);
  if (lane == 0) sB[row] = (float)(1.0 - 3.0 * bs);
}

// ---------------- fp32 GEMM  C = act(A * Bt^T + bias) ----------------
// A: [M][K], Bt: [N][K]; BM=BN=64, BK=128, 256 threads, 4x4 microtile
template <int ACT>
__global__ __launch_bounds__(256) void gemm64(const float* __restrict__ A,
                                              const float* __restrict__ Bt,
                                              const float* __restrict__ bias,
                                              float* __restrict__ C,
                                              int M, int N, int K) {
  __shared__ __align__(16) float As[64 * 128];
  __shared__ __align__(16) float Bs[64 * 128];
  const int tx = threadIdx.x & 15, ty = threadIdx.x >> 4;
  const int brow = blockIdx.x * 64, bcol = blockIdx.y * 64;
  float acc[4][4] = {};
  const int r0 = threadIdx.x >> 5;  // 0..7
  const int c0 = threadIdx.x & 31;  // 0..31, k-block of 4 floats

  for (int kb = 0; kb < K; kb += 128) {
#pragma unroll
    for (int s = 0; s < 8; ++s) {
      int r = r0 + 8 * s;
      int sw = ((c0 ^ (r & 31)) << 2);
      *reinterpret_cast<float4*>(&As[r * 128 + sw]) =
          *reinterpret_cast<const float4*>(&A[(size_t)(brow + r) * K + kb + c0 * 4]);
      *reinterpret_cast<float4*>(&Bs[r * 128 + sw]) =
          *reinterpret_cast<const float4*>(&Bt[(size_t)(bcol + r) * K + kb + c0 * 4]);
    }
    __syncthreads();
#pragma unroll
    for (int kk = 0; kk < 32; ++kk) {
      float4 a[4], b[4];
#pragma unroll
      for (int i = 0; i < 4; ++i) {
        int m = ty + 16 * i;
        a[i] = *reinterpret_cast<const float4*>(&As[m * 128 + ((kk ^ (m & 31)) << 2)]);
      }
#pragma unroll
      for (int j = 0; j < 4; ++j) {
        int n = tx + 16 * j;
        b[j] = *reinterpret_cast<const float4*>(&Bs[n * 128 + ((kk ^ (n & 31)) << 2)]);
      }
#pragma unroll
      for (int i = 0; i < 4; ++i)
#pragma unroll
        for (int j = 0; j < 4; ++j) {
          acc[i][j] += a[i].x * b[j].x;
          acc[i][j] += a[i].y * b[j].y;
          acc[i][j] += a[i].z * b[j].z;
          acc[i][j] += a[i].w * b[j].w;
        }
    }
    __syncthreads();
  }
#pragma unroll
  for (int i = 0; i < 4; ++i) {
    int m = brow + ty + 16 * i;
#pragma unroll
    for (int j = 0; j < 4; ++j) {
      int n = bcol + tx + 16 * j;
      float v = acc[i][j] + bias[n];
      if (ACT) v = 0.5f * v * (1.0f + erff(v * 0.70710678f));
      C[(size_t)m * N + n] = v;
    }
  }
}

// ---------------- distance kernel ----------------
// P = hyp @ proto^T, then stable Poincare distance epilogue.
// BM=BN=128, K=128 in two 64-chunks, 256 threads, 8x8 interleaved microtile.
__global__ __launch_bounds__(256) void dist_kernel(const float* __restrict__ hyp,
                                                   const float* __restrict__ proto,
                                                   const float* __restrict__ An,
                                                   const float* __restrict__ sB,
                                                   float* __restrict__ out) {
  __shared__ __align__(16) float Hs[128 * 64];
  __shared__ __align__(16) float Ps[128 * 64];
  const int tx = threadIdx.x & 15, ty = threadIdx.x >> 4;
  const int brow = blockIdx.y * 128, bcol = blockIdx.x * 128;
  float acc[8][8] = {};
  const int r0 = threadIdx.x >> 4;  // 0..15
  const int c0 = threadIdx.x & 15;  // 0..15, k-block of 4 floats (64 k)

  for (int kb = 0; kb < 128; kb += 64) {
#pragma unroll
    for (int s = 0; s < 8; ++s) {
      int r = r0 + 16 * s;
      int sw = ((c0 ^ (r & 15)) << 2);
      *reinterpret_cast<float4*>(&Hs[r * 64 + sw]) =
          *reinterpret_cast<const float4*>(&hyp[(size_t)(brow + r) * DD + kb + c0 * 4]);
      *reinterpret_cast<float4*>(&Ps[r * 64 + sw]) =
          *reinterpret_cast<const float4*>(&proto[(size_t)(bcol + r) * DD + kb + c0 * 4]);
    }
    __syncthreads();
#pragma unroll
    for (int kk = 0; kk < 16; ++kk) {
      float4 a[8], b[8];
#pragma unroll
      for (int i = 0; i < 8; ++i) {
        int m = ty + 16 * i;
        a[i] = *reinterpret_cast<const float4*>(&Hs[m * 64 + ((kk ^ (m & 15)) << 2)]);
      }
#pragma unroll
      for (int j = 0; j < 8; ++j) {
        int n = tx + 16 * j;
        b[j] = *reinterpret_cast<const float4*>(&Ps[n * 64 + ((kk ^ (n & 15)) << 2)]);
      }
#pragma unroll
      for (int i = 0; i < 8; ++i)
#pragma unroll
        for (int j = 0; j < 8; ++j) {
          acc[i][j] += a[i].x * b[j].x;
          acc[i][j] += a[i].y * b[j].y;
          acc[i][j] += a[i].z * b[j].z;
          acc[i][j] += a[i].w * b[j].w;
        }
    }
    __syncthreads();
  }

  // Epilogue: alpha = 1-6P+3B, beta = 1-3A, den = 1-6P+9AB
  // Stable: 1-arg = beta*sB / (den + sqrt(3*ns)),  sB = 1-3*Bn (fp64-derived)
  float aa[8], beta[8], a9[8], bbv[8], sBv[8];
#pragma unroll
  for (int j = 0; j < 8; ++j) {
    aa[j] = An[bcol + tx + 16 * j];
    beta[j] = 1.0f - 3.0f * aa[j];
    a9[j] = 9.0f * aa[j];
  }
#pragma unroll
  for (int i = 0; i < 8; ++i) {
    float s = sB[brow + ty + 16 * i];
    sBv[i] = s;
    bbv[i] = (1.0f - s) * 0.33333334f;
  }
#pragma unroll
  for (int i = 0; i < 8; ++i) {
    size_t m = (size_t)(brow + ty + 16 * i);
#pragma unroll
    for (int j = 0; j < 8; ++j) {
      float P = acc[i][j];
      float t6 = fmaf(-6.0f, P, 1.0f);          // 1 - 6P
      float alpha = fmaf(3.0f, bbv[i], t6);     // 1 - 6P + 3B
      float den = fmaf(a9[j], bbv[i], t6);      // 1 - 6P + 9AB
      den = fmaxf(den, 1e-15f);
      float ns = alpha * alpha * aa[j] + beta[j] * beta[j] * bbv[i]
                 - 2.0f * alpha * beta[j] * P;
      ns = fmaxf(ns, 1e-15f);
      float om = beta[j] * sBv[i] / (den + sqrtf(3.0f * ns));
      om = fmaxf(om, 1e-5f);                    // == clamp arg <= 1-1e-5
      float ratio = __fdividef(2.0f - om, om);  // (1+arg)/(1-arg)
      out[m * NN + (bcol + tx + 16 * j)] = -8.247861f * __logf(ratio);
    }
  }
}

extern "C" void kernel_launch(void* const* d_in, const int* in_sizes, int n_in,
                              void* d_out, int out_size, void* d_ws, size_t ws_size,
                              hipStream_t stream) {
  const float* x  = (const float*)d_in[0];
  const float* W1 = (const float*)d_in[1];
  const float* b1 = (const float*)d_in[2];
  const float* W2 = (const float*)d_in[3];
  const float* b2 = (const float*)d_in[4];
  const float* W3 = (const float*)d_in[5];
  const float* b3 = (const float*)d_in[6];
  const float* proto = (const float*)d_in[7];

  float* logits = (float*)d_out;
  float* hyp = logits + (size_t)BB * NN;

  float* ws  = (float*)d_ws;
  float* Wt1 = ws;                       // 256*768
  float* Wt2 = Wt1 + 256 * 768;          // 256*256
  float* Wt3 = Wt2 + 256 * 256;          // 128*256
  float* h1  = Wt3 + 128 * 256;          // 4096*256
  float* h2  = h1 + (size_t)4096 * 256;  // 4096*256
  float* uu  = h2 + (size_t)4096 * 256;  // 4096*128
  float* An  = uu + (size_t)4096 * 128;  // 16384
  float* sB  = An + 16384;               // 4096

  transpose_kernel<<<dim3(8, 24), dim3(32, 8), 0, stream>>>(W1, Wt1, 768, 256);
  transpose_kernel<<<dim3(8, 8), dim3(32, 8), 0, stream>>>(W2, Wt2, 256, 256);
  transpose_kernel<<<dim3(4, 8), dim3(32, 8), 0, stream>>>(W3, Wt3, 256, 128);
  proto_norms<<<4096, 256, 0, stream>>>(proto, An);

  gemm64<1><<<dim3(64, 4), 256, 0, stream>>>(x, Wt1, b1, h1, 4096, 256, 768);
  gemm64<1><<<dim3(64, 4), 256, 0, stream>>>(h1, Wt2, b2, h2, 4096, 256, 256);
  gemm64<0><<<dim3(64, 2), 256, 0, stream>>>(h2, Wt3, b3, uu, 4096, 128, 256);

  expmap_kernel<<<1024, 256, 0, stream>>>(uu, hyp, sB);

  dist_kernel<<<dim3(128, 32), 256, 0, stream>>>(hyp, proto, An, sB, logits);
}

// Round 2
// 266.557 us; speedup vs baseline: 2.4118x; 2.4118x over previous
//
#include <hip/hip_runtime.h>
#include <math.h>

#define BB 4096
#define FIN 768
#define HH 256
#define DD 128
#define NN 16384

typedef _Float16 half8 __attribute__((ext_vector_type(8)));
typedef _Float16 half4 __attribute__((ext_vector_type(4)));
typedef float floatx4 __attribute__((ext_vector_type(4)));

// ---------------- transpose: out[n][k] = in[k][n], in is K x N row-major ----
__global__ void transpose_kernel(const float* __restrict__ in, float* __restrict__ out,
                                 int K, int N) {
  __shared__ float tile[32][33];
  int k0 = blockIdx.y * 32, n0 = blockIdx.x * 32;
  int tx = threadIdx.x, ty = threadIdx.y; // 32 x 8
  for (int r = ty; r < 32; r += 8) {
    tile[r][tx] = in[(size_t)(k0 + r) * N + (n0 + tx)];
  }
  __syncthreads();
  for (int r = ty; r < 32; r += 8) {
    out[(size_t)(n0 + r) * K + (k0 + tx)] = tile[tx][r];
  }
}

// ---------------- prototype squared norms ----------------
__global__ void proto_norms(const float* __restrict__ p, float* __restrict__ An) {
  int row = blockIdx.x * 4 + (threadIdx.x >> 6);
  int lane = threadIdx.x & 63;
  float v0 = p[(size_t)row * DD + lane], v1 = p[(size_t)row * DD + 64 + lane];
  float s = v0 * v0 + v1 * v1;
  for (int off = 32; off; off >>= 1) s += __shfl_xor(s, off);
  if (lane == 0) An[row] = s;
}

// ---------------- expmap0 + stable (1 - 3*Bn) in fp64 ----------------
__global__ void expmap_kernel(const float* __restrict__ u, float* __restrict__ hyp,
                              float* __restrict__ sB) {
  int row = blockIdx.x * 4 + (threadIdx.x >> 6);
  int lane = threadIdx.x & 63;
  float u0 = u[(size_t)row * DD + lane], u1 = u[(size_t)row * DD + 64 + lane];
  double s = (double)u0 * u0 + (double)u1 * u1;
  for (int off = 32; off; off >>= 1) s += __shfl_xor(s, off);
  double un = sqrt(s);
  if (un < 1e-15) un = 1e-15;
  double t = 1.7320508075688772 * un;
  double factor = tanh(t) / t;
  float h0 = (float)(factor * u0), h1 = (float)(factor * u1);
  hyp[(size_t)row * DD + lane] = h0;
  hyp[(size_t)row * DD + 64 + lane] = h1;
  double bs = (double)h0 * h0 + (double)h1 * h1;
  for (int off = 32; off; off >>= 1) bs += __shfl_xor(bs, off);
  if (lane == 0) sB[row] = (float)(1.0 - 3.0 * bs);
}

// ---------------- fp32 GEMM  C = act(A * Bt^T + bias) ----------------
template <int ACT>
__global__ __launch_bounds__(256) void gemm64(const float* __restrict__ A,
                                              const float* __restrict__ Bt,
                                              const float* __restrict__ bias,
                                              float* __restrict__ C,
                                              int M, int N, int K) {
  __shared__ __align__(16) float As[64 * 128];
  __shared__ __align__(16) float Bs[64 * 128];
  const int tx = threadIdx.x & 15, ty = threadIdx.x >> 4;
  const int brow = blockIdx.x * 64, bcol = blockIdx.y * 64;
  float acc[4][4] = {};
  const int r0 = threadIdx.x >> 5;
  const int c0 = threadIdx.x & 31;

  for (int kb = 0; kb < K; kb += 128) {
#pragma unroll
    for (int s = 0; s < 8; ++s) {
      int r = r0 + 8 * s;
      int sw = ((c0 ^ (r & 31)) << 2);
      *reinterpret_cast<float4*>(&As[r * 128 + sw]) =
          *reinterpret_cast<const float4*>(&A[(size_t)(brow + r) * K + kb + c0 * 4]);
      *reinterpret_cast<float4*>(&Bs[r * 128 + sw]) =
          *reinterpret_cast<const float4*>(&Bt[(size_t)(bcol + r) * K + kb + c0 * 4]);
    }
    __syncthreads();
#pragma unroll
    for (int kk = 0; kk < 32; ++kk) {
      float4 a[4], b[4];
#pragma unroll
      for (int i = 0; i < 4; ++i) {
        int m = ty + 16 * i;
        a[i] = *reinterpret_cast<const float4*>(&As[m * 128 + ((kk ^ (m & 31)) << 2)]);
      }
#pragma unroll
      for (int j = 0; j < 4; ++j) {
        int n = tx + 16 * j;
        b[j] = *reinterpret_cast<const float4*>(&Bs[n * 128 + ((kk ^ (n & 31)) << 2)]);
      }
#pragma unroll
      for (int i = 0; i < 4; ++i)
#pragma unroll
        for (int j = 0; j < 4; ++j) {
          acc[i][j] += a[i].x * b[j].x;
          acc[i][j] += a[i].y * b[j].y;
          acc[i][j] += a[i].z * b[j].z;
          acc[i][j] += a[i].w * b[j].w;
        }
    }
    __syncthreads();
  }
#pragma unroll
  for (int i = 0; i < 4; ++i) {
    int m = brow + ty + 16 * i;
#pragma unroll
    for (int j = 0; j < 4; ++j) {
      int n = bcol + tx + 16 * j;
      float v = acc[i][j] + bias[n];
      if (ACT) v = 0.5f * v * (1.0f + erff(v * 0.70710678f));
      C[(size_t)m * N + n] = v;
    }
  }
}

// ---------------- distance kernel: fp16-split MFMA GEMM + stable epilogue ---
// P = Hhi*Phi + Hhi*Plo + Hlo*Phi  (lo*lo dropped, ~1e-7)
// 128x128 tile, 4 waves (2x2 of 64x64), K=128 in two BK=64 steps.
// LDS: Ahi/Alo/Bhi/Blo each [128 rows][64 k] f16 = 16KB, XOR-swizzled 16B blocks.
__global__ __launch_bounds__(256) void dist_mfma(const float* __restrict__ hyp,
                                                 const float* __restrict__ proto,
                                                 const float* __restrict__ An,
                                                 const float* __restrict__ sB,
                                                 float* __restrict__ out) {
  __shared__ __align__(16) char smem[65536];
  const int AHI = 0, ALO = 16384, BHI = 32768, BLO = 49152;

  const int tid = threadIdx.x;
  const int lane = tid & 63;
  const int wave = tid >> 6;        // 0..3
  const int wr = wave >> 1, wc = wave & 1;
  const int l15 = lane & 15, lg = lane >> 4;  // frag row/col, k-group

  const int brow = blockIdx.y * 128, bcol = blockIdx.x * 128;

  floatx4 acc[4][4] = {};

  const int sr = tid >> 4;   // 0..15 staging row base
  const int k4 = tid & 15;   // float4 index within 64-k chunk

  for (int kb = 0; kb < 128; kb += 64) {
    // ---- stage + split: fp32 -> (hi,lo) f16, swizzled ds_write_b64 ----
#pragma unroll
    for (int s = 0; s < 8; ++s) {
      int row = sr + 16 * s;
      float4 av = *reinterpret_cast<const float4*>(&hyp[(size_t)(brow + row) * DD + kb + k4 * 4]);
      float4 bv = *reinterpret_cast<const float4*>(&proto[(size_t)(bcol + row) * DD + kb + k4 * 4]);
      half4 ahi, alo, bhi, blo;
      ahi[0] = (_Float16)av.x; alo[0] = (_Float16)(av.x - (float)ahi[0]);
      ahi[1] = (_Float16)av.y; alo[1] = (_Float16)(av.y - (float)ahi[1]);
      ahi[2] = (_Float16)av.z; alo[2] = (_Float16)(av.z - (float)ahi[2]);
      ahi[3] = (_Float16)av.w; alo[3] = (_Float16)(av.w - (float)ahi[3]);
      bhi[0] = (_Float16)bv.x; blo[0] = (_Float16)(bv.x - (float)bhi[0]);
      bhi[1] = (_Float16)bv.y; blo[1] = (_Float16)(bv.y - (float)bhi[1]);
      bhi[2] = (_Float16)bv.z; blo[2] = (_Float16)(bv.z - (float)bhi[2]);
      bhi[3] = (_Float16)bv.w; blo[3] = (_Float16)(bv.w - (float)bhi[3]);
      int off = row * 128 + ((k4 * 8) ^ ((row & 7) << 4));
      *reinterpret_cast<half4*>(&smem[AHI + off]) = ahi;
      *reinterpret_cast<half4*>(&smem[ALO + off]) = alo;
      *reinterpret_cast<half4*>(&smem[BHI + off]) = bhi;
      *reinterpret_cast<half4*>(&smem[BLO + off]) = blo;
    }
    __syncthreads();

    // ---- MFMA phase: 2 k-chunks of 32 ----
#pragma unroll
    for (int kkb = 0; kkb < 8; kkb += 4) {
      half8 fahi[4], falo[4], fbhi[4], fblo[4];
      int k8 = kkb + lg;
#pragma unroll
      for (int f = 0; f < 4; ++f) {
        int rA = wr * 64 + f * 16 + l15;
        int offA = rA * 128 + ((k8 << 4) ^ ((rA & 7) << 4));
        fahi[f] = *reinterpret_cast<const half8*>(&smem[AHI + offA]);
        falo[f] = *reinterpret_cast<const half8*>(&smem[ALO + offA]);
        int rB = wc * 64 + f * 16 + l15;
        int offB = rB * 128 + ((k8 << 4) ^ ((rB & 7) << 4));
        fbhi[f] = *reinterpret_cast<const half8*>(&smem[BHI + offB]);
        fblo[f] = *reinterpret_cast<const half8*>(&smem[BLO + offB]);
      }
#pragma unroll
      for (int i = 0; i < 4; ++i)
#pragma unroll
        for (int j = 0; j < 4; ++j) {
          acc[i][j] = __builtin_amdgcn_mfma_f32_16x16x32_f16(fahi[i], fbhi[j], acc[i][j], 0, 0, 0);
          acc[i][j] = __builtin_amdgcn_mfma_f32_16x16x32_f16(fahi[i], fblo[j], acc[i][j], 0, 0, 0);
          acc[i][j] = __builtin_amdgcn_mfma_f32_16x16x32_f16(falo[i], fbhi[j], acc[i][j], 0, 0, 0);
        }
    }
    __syncthreads();
  }

  // ---- epilogue: stable Poincare distance ----
  // alpha = 1-6P+3B, beta = 1-3A, den = 1-6P+9AB
  // 1-arg = beta*sB / (den + sqrt(3*ns)),  sB = 1-3*Bn (fp64-derived)
  float aa[4], beta[4], a9[4];
#pragma unroll
  for (int j = 0; j < 4; ++j) {
    aa[j] = An[bcol + wc * 64 + j * 16 + l15];
    beta[j] = 1.0f - 3.0f * aa[j];
    a9[j] = 9.0f * aa[j];
  }
#pragma unroll
  for (int i = 0; i < 4; ++i) {
#pragma unroll
    for (int t = 0; t < 4; ++t) {
      int row = brow + wr * 64 + i * 16 + lg * 4 + t;
      float s = sB[row];
      float bbv = (1.0f - s) * 0.33333334f;
      size_t orow = (size_t)row * NN;
#pragma unroll
      for (int j = 0; j < 4; ++j) {
        float P = acc[i][j][t];
        float t6 = fmaf(-6.0f, P, 1.0f);
        float alpha = fmaf(3.0f, bbv, t6);
        float den = fmaf(a9[j], bbv, t6);
        den = fmaxf(den, 1e-15f);
        float ns = alpha * alpha * aa[j] + beta[j] * beta[j] * bbv
                   - 2.0f * alpha * beta[j] * P;
        ns = fmaxf(ns, 1e-15f);
        float om = beta[j] * s / (den + sqrtf(3.0f * ns));
        om = fmaxf(om, 1e-5f);
        float ratio = __fdividef(2.0f - om, om);
        out[orow + (bcol + wc * 64 + j * 16 + l15)] = -8.247861f * __logf(ratio);
      }
    }
  }
}

extern "C" void kernel_launch(void* const* d_in, const int* in_sizes, int n_in,
                              void* d_out, int out_size, void* d_ws, size_t ws_size,
                              hipStream_t stream) {
  const float* x  = (const float*)d_in[0];
  const float* W1 = (const float*)d_in[1];
  const float* b1 = (const float*)d_in[2];
  const float* W2 = (const float*)d_in[3];
  const float* b2 = (const float*)d_in[4];
  const float* W3 = (const float*)d_in[5];
  const float* b3 = (const float*)d_in[6];
  const float* proto = (const float*)d_in[7];

  float* logits = (float*)d_out;
  float* hyp = logits + (size_t)BB * NN;

  float* ws  = (float*)d_ws;
  float* Wt1 = ws;                       // 256*768
  float* Wt2 = Wt1 + 256 * 768;          // 256*256
  float* Wt3 = Wt2 + 256 * 256;          // 128*256
  float* h1  = Wt3 + 128 * 256;          // 4096*256
  float* h2  = h1 + (size_t)4096 * 256;  // 4096*256
  float* uu  = h2 + (size_t)4096 * 256;  // 4096*128
  float* An  = uu + (size_t)4096 * 128;  // 16384
  float* sB  = An + 16384;               // 4096

  transpose_kernel<<<dim3(8, 24), dim3(32, 8), 0, stream>>>(W1, Wt1, 768, 256);
  transpose_kernel<<<dim3(8, 8), dim3(32, 8), 0, stream>>>(W2, Wt2, 256, 256);
  transpose_kernel<<<dim3(4, 8), dim3(32, 8), 0, stream>>>(W3, Wt3, 256, 128);
  proto_norms<<<4096, 256, 0, stream>>>(proto, An);

  gemm64<1><<<dim3(64, 4), 256, 0, stream>>>(x, Wt1, b1, h1, 4096, 256, 768);
  gemm64<1><<<dim3(64, 4), 256, 0, stream>>>(h1, Wt2, b2, h2, 4096, 256, 256);
  gemm64<0><<<dim3(64, 2), 256, 0, stream>>>(h2, Wt3, b3, uu, 4096, 128, 256);

  expmap_kernel<<<1024, 256, 0, stream>>>(uu, hyp, sB);

  dist_mfma<<<dim3(128, 32), 256, 0, stream>>>(hyp, proto, An, sB, logits);
}

// Round 3
// 224.171 us; speedup vs baseline: 2.8678x; 1.1891x over previous
//
#include <hip/hip_runtime.h>
#include <math.h>

#define BB 4096
#define FIN 768
#define HH 256
#define DD 128
#define NN 16384

typedef _Float16 half8 __attribute__((ext_vector_type(8)));
typedef float floatx4 __attribute__((ext_vector_type(4)));

// ---------------- transpose: out[n][k] = in[k][n], in is K x N row-major ----
__global__ void transpose_kernel(const float* __restrict__ in, float* __restrict__ out,
                                 int K, int N) {
  __shared__ float tile[32][33];
  int k0 = blockIdx.y * 32, n0 = blockIdx.x * 32;
  int tx = threadIdx.x, ty = threadIdx.y; // 32 x 8
  for (int r = ty; r < 32; r += 8) {
    tile[r][tx] = in[(size_t)(k0 + r) * N + (n0 + tx)];
  }
  __syncthreads();
  for (int r = ty; r < 32; r += 8) {
    out[(size_t)(n0 + r) * K + (k0 + tx)] = tile[tx][r];
  }
}

// ---------------- proto prep: f16 hi/lo split in fragment layout + beta -----
// Fragment layout (halves): dest = (row>>4)*2048 + (ks*4+lg)*128 + (row&15)*8 + e
// where k = ks*32 + lg*8 + e.
__global__ void proto_prep(const float* __restrict__ p, _Float16* __restrict__ BHf,
                           _Float16* __restrict__ BLf, float* __restrict__ beta) {
  int row = blockIdx.x * 4 + (threadIdx.x >> 6);
  int l = threadIdx.x & 63;
  float v0 = p[(size_t)row * DD + l], v1 = p[(size_t)row * DD + 64 + l];
  double s = (double)v0 * v0 + (double)v1 * v1;
  for (int off = 32; off; off >>= 1) s += __shfl_xor(s, off);
  if (l == 0) beta[row] = (float)(1.0 - 3.0 * s);
  _Float16 h0 = (_Float16)v0; _Float16 lo0 = (_Float16)(v0 - (float)h0);
  _Float16 h1 = (_Float16)v1; _Float16 lo1 = (_Float16)(v1 - (float)h1);
  int g = row >> 4, lr = row & 15, lg = (l >> 3) & 3, e = l & 7;
  size_t d0 = (size_t)g * 2048 + (size_t)(((l >> 5)) * 4 + lg) * 128 + lr * 8 + e;
  size_t d1 = (size_t)g * 2048 + (size_t)((2 + (l >> 5)) * 4 + lg) * 128 + lr * 8 + e;
  BHf[d0] = h0; BLf[d0] = lo0;
  BHf[d1] = h1; BLf[d1] = lo1;
}

// ---------------- expmap0 + hyp out + A fragments + sB (fp64) ----------------
__global__ void expmap_prep(const float* __restrict__ u, float* __restrict__ hyp,
                            _Float16* __restrict__ AHf, _Float16* __restrict__ ALf,
                            float* __restrict__ sB) {
  int row = blockIdx.x * 4 + (threadIdx.x >> 6);
  int l = threadIdx.x & 63;
  float u0 = u[(size_t)row * DD + l], u1 = u[(size_t)row * DD + 64 + l];
  double s = (double)u0 * u0 + (double)u1 * u1;
  for (int off = 32; off; off >>= 1) s += __shfl_xor(s, off);
  double un = sqrt(s);
  if (un < 1e-15) un = 1e-15;
  double t = 1.7320508075688772 * un;
  double factor = tanh(t) / t;
  float h0 = (float)(factor * u0), h1 = (float)(factor * u1);
  hyp[(size_t)row * DD + l] = h0;
  hyp[(size_t)row * DD + 64 + l] = h1;
  double bs = (double)h0 * h0 + (double)h1 * h1;
  for (int off = 32; off; off >>= 1) bs += __shfl_xor(bs, off);
  if (l == 0) sB[row] = (float)(1.0 - 3.0 * bs);
  _Float16 hh0 = (_Float16)h0; _Float16 lo0 = (_Float16)(h0 - (float)hh0);
  _Float16 hh1 = (_Float16)h1; _Float16 lo1 = (_Float16)(h1 - (float)hh1);
  int g = row >> 4, lr = row & 15, lg = (l >> 3) & 3, e = l & 7;
  size_t d0 = (size_t)g * 2048 + (size_t)(((l >> 5)) * 4 + lg) * 128 + lr * 8 + e;
  size_t d1 = (size_t)g * 2048 + (size_t)((2 + (l >> 5)) * 4 + lg) * 128 + lr * 8 + e;
  AHf[d0] = hh0; ALf[d0] = lo0;
  AHf[d1] = hh1; ALf[d1] = lo1;
}

// ---------------- fp32 GEMM  C = act(A * Bt^T + bias) (MLP) ----------------
template <int ACT>
__global__ __launch_bounds__(256) void gemm64(const float* __restrict__ A,
                                              const float* __restrict__ Bt,
                                              const float* __restrict__ bias,
                                              float* __restrict__ C,
                                              int M, int N, int K) {
  __shared__ __align__(16) float As[64 * 128];
  __shared__ __align__(16) float Bs[64 * 128];
  const int tx = threadIdx.x & 15, ty = threadIdx.x >> 4;
  const int brow = blockIdx.x * 64, bcol = blockIdx.y * 64;
  float acc[4][4] = {};
  const int r0 = threadIdx.x >> 5;
  const int c0 = threadIdx.x & 31;

  for (int kb = 0; kb < K; kb += 128) {
#pragma unroll
    for (int s = 0; s < 8; ++s) {
      int r = r0 + 8 * s;
      int sw = ((c0 ^ (r & 31)) << 2);
      *reinterpret_cast<float4*>(&As[r * 128 + sw]) =
          *reinterpret_cast<const float4*>(&A[(size_t)(brow + r) * K + kb + c0 * 4]);
      *reinterpret_cast<float4*>(&Bs[r * 128 + sw]) =
          *reinterpret_cast<const float4*>(&Bt[(size_t)(bcol + r) * K + kb + c0 * 4]);
    }
    __syncthreads();
#pragma unroll
    for (int kk = 0; kk < 32; ++kk) {
      float4 a[4], b[4];
#pragma unroll
      for (int i = 0; i < 4; ++i) {
        int m = ty + 16 * i;
        a[i] = *reinterpret_cast<const float4*>(&As[m * 128 + ((kk ^ (m & 31)) << 2)]);
      }
#pragma unroll
      for (int j = 0; j < 4; ++j) {
        int n = tx + 16 * j;
        b[j] = *reinterpret_cast<const float4*>(&Bs[n * 128 + ((kk ^ (n & 31)) << 2)]);
      }
#pragma unroll
      for (int i = 0; i < 4; ++i)
#pragma unroll
        for (int j = 0; j < 4; ++j) {
          acc[i][j] += a[i].x * b[j].x;
          acc[i][j] += a[i].y * b[j].y;
          acc[i][j] += a[i].z * b[j].z;
          acc[i][j] += a[i].w * b[j].w;
        }
    }
    __syncthreads();
  }
#pragma unroll
  for (int i = 0; i < 4; ++i) {
    int m = brow + ty + 16 * i;
#pragma unroll
    for (int j = 0; j < 4; ++j) {
      int n = bcol + tx + 16 * j;
      float v = acc[i][j] + bias[n];
      if (ACT) v = 0.5f * v * (1.0f + erff(v * 0.70710678f));
      C[(size_t)m * N + n] = v;
    }
  }
}

// ---------------- distance kernel: register-only MFMA + identity epilogue ---
// P = Hhi*Phi + Hhi*Plo + Hlo*Phi ; fragments pre-linearized in global memory.
// No LDS, no barriers. 128x128 tile, 4 waves (2x2), K=128 in 4 ksteps, 2-deep
// prefetch with static double buffers.
__global__ __launch_bounds__(256, 2) void dist_mfma(
    const _Float16* __restrict__ AH, const _Float16* __restrict__ AL,
    const _Float16* __restrict__ BH, const _Float16* __restrict__ BL,
    const float* __restrict__ beta, const float* __restrict__ sB,
    float* __restrict__ out) {
  const int tid = threadIdx.x, lane = tid & 63, wave = tid >> 6;
  const int wr = wave >> 1, wc = wave & 1;
  const int l15 = lane & 15, lg = lane >> 4;
  const int brow = blockIdx.y * 128, bcol = blockIdx.x * 128;

  const size_t aB = (size_t)((brow >> 4) + wr * 4) * 2048 + (size_t)lg * 128 + l15 * 8;
  const size_t bB = (size_t)((bcol >> 4) + wc * 4) * 2048 + (size_t)lg * 128 + l15 * 8;

  floatx4 acc[4][4] = {};
  half8 pah[4], pal[4], pbh[4], pbl[4];
  half8 qah[4], qal[4], qbh[4], qbl[4];

#define LOADF(Dah, Dal, Dbh, Dbl, KS)                                      \
  _Pragma("unroll") for (int f = 0; f < 4; ++f) {                          \
    Dah[f] = *(const half8*)&AH[aB + (size_t)f * 2048 + (KS) * 512];       \
    Dal[f] = *(const half8*)&AL[aB + (size_t)f * 2048 + (KS) * 512];       \
    Dbh[f] = *(const half8*)&BH[bB + (size_t)f * 2048 + (KS) * 512];       \
    Dbl[f] = *(const half8*)&BL[bB + (size_t)f * 2048 + (KS) * 512];       \
  }

#define MSTEP(Sah, Sal, Sbh, Sbl)                                          \
  _Pragma("unroll") for (int i = 0; i < 4; ++i) {                          \
    _Pragma("unroll") for (int j = 0; j < 4; ++j) {                        \
      acc[i][j] = __builtin_amdgcn_mfma_f32_16x16x32_f16(Sah[i], Sbh[j], acc[i][j], 0, 0, 0); \
      acc[i][j] = __builtin_amdgcn_mfma_f32_16x16x32_f16(Sah[i], Sbl[j], acc[i][j], 0, 0, 0); \
      acc[i][j] = __builtin_amdgcn_mfma_f32_16x16x32_f16(Sal[i], Sbh[j], acc[i][j], 0, 0, 0); \
    }                                                                      \
  }

  LOADF(pah, pal, pbh, pbl, 0)
  LOADF(qah, qal, qbh, qbl, 1)
  MSTEP(pah, pal, pbh, pbl)
  LOADF(pah, pal, pbh, pbl, 2)
  MSTEP(qah, qal, qbh, qbl)
  LOADF(qah, qal, qbh, qbl, 3)
  MSTEP(pah, pal, pbh, pbl)
  MSTEP(qah, qal, qbh, qbl)
#undef LOADF
#undef MSTEP

  // Epilogue. den = 1-6P+9AB; bs = beta*sB; 3*num_sq = den*(den-bs) (exact id)
  // om = 1-arg = bs/(den+sqrt(den*(den-bs))); logits = -C*(log2(2-om)-log2(om))
  float bet[4], a9[4];
#pragma unroll
  for (int j = 0; j < 4; ++j) {
    bet[j] = beta[bcol + wc * 64 + j * 16 + l15];
    a9[j] = 3.0f * (1.0f - bet[j]);  // = 9*A
  }
#pragma unroll
  for (int i = 0; i < 4; ++i) {
#pragma unroll
    for (int t = 0; t < 4; ++t) {
      int row = brow + wr * 64 + i * 16 + lg * 4 + t;
      float s = sB[row];
      float bb = (1.0f - s) * 0.33333334f;  // = B
      size_t orow = (size_t)row * NN;
#pragma unroll
      for (int j = 0; j < 4; ++j) {
        float P = acc[i][j][t];
        float t6 = fmaf(-6.0f, P, 1.0f);
        float den = fmaf(a9[j], bb, t6);
        den = fmaxf(den, 1e-15f);
        float bs = bet[j] * s;
        float q = den * (den - bs);
        q = fmaxf(q, 0.0f);
        float om = __fdividef(bs, den + sqrtf(q));
        om = fmaxf(om, 1e-5f);
        out[orow + bcol + wc * 64 + j * 16 + l15] =
            -5.7169818f * (__log2f(2.0f - om) - __log2f(om));
      }
    }
  }
}

extern "C" void kernel_launch(void* const* d_in, const int* in_sizes, int n_in,
                              void* d_out, int out_size, void* d_ws, size_t ws_size,
                              hipStream_t stream) {
  const float* x  = (const float*)d_in[0];
  const float* W1 = (const float*)d_in[1];
  const float* b1 = (const float*)d_in[2];
  const float* W2 = (const float*)d_in[3];
  const float* b2 = (const float*)d_in[4];
  const float* W3 = (const float*)d_in[5];
  const float* b3 = (const float*)d_in[6];
  const float* proto = (const float*)d_in[7];

  float* logits = (float*)d_out;
  float* hyp = logits + (size_t)BB * NN;

  float* ws   = (float*)d_ws;
  float* h1   = ws;                      // 4096*256 = 1048576 f
  float* h2   = ws + 1048576;            // 1048576 f
  float* uu   = ws + 2097152;            // 4096*128 = 524288 f
  float* Wt1  = ws + 2621440;            // 196608 f
  float* Wt2  = ws + 2818048;            // 65536 f
  float* Wt3  = ws + 2883584;            // 32768 f
  float* beta = ws + 2916352;            // 16384 f
  float* sB   = ws + 2932736;            // 4096 f
  _Float16* AHf = (_Float16*)(ws + 2936832);  // 4096*128 halves
  _Float16* ALf = AHf + (size_t)4096 * 128;
  // B fragments alias h1/h2 (dead after gemm3): 16384*128 halves = 4MB each
  _Float16* BHf = (_Float16*)h1;
  _Float16* BLf = (_Float16*)h2;

  transpose_kernel<<<dim3(8, 24), dim3(32, 8), 0, stream>>>(W1, Wt1, 768, 256);
  transpose_kernel<<<dim3(8, 8), dim3(32, 8), 0, stream>>>(W2, Wt2, 256, 256);
  transpose_kernel<<<dim3(4, 8), dim3(32, 8), 0, stream>>>(W3, Wt3, 256, 128);

  gemm64<1><<<dim3(64, 4), 256, 0, stream>>>(x, Wt1, b1, h1, 4096, 256, 768);
  gemm64<1><<<dim3(64, 4), 256, 0, stream>>>(h1, Wt2, b2, h2, 4096, 256, 256);
  gemm64<0><<<dim3(64, 2), 256, 0, stream>>>(h2, Wt3, b3, uu, 4096, 128, 256);

  // after gemm3, h1/h2 are dead -> reuse for proto fragments
  proto_prep<<<4096, 256, 0, stream>>>(proto, BHf, BLf, beta);
  expmap_prep<<<1024, 256, 0, stream>>>(uu, hyp, AHf, ALf, sB);

  dist_mfma<<<dim3(128, 32), 256, 0, stream>>>(AHf, ALf, BHf, BLf, beta, sB, logits);
}